// Round 10
// baseline (250.053 us; speedup 1.0000x reference)
//
#include <hip/hip_runtime.h>
#include <hip/hip_bf16.h>
#include <math.h>

#define Bn 8
#define Sn 1024
#define Dn 768
#define Hn 12
#define MROWS (Bn * Sn)

typedef __attribute__((ext_vector_type(8))) short short8;
typedef __attribute__((ext_vector_type(4))) float floatx4;

__device__ __forceinline__ unsigned short f2b(float x) {
    union { float f; unsigned u; } v; v.f = x;
    unsigned r = v.u + 0x7fffu + ((v.u >> 16) & 1u);
    return (unsigned short)(r >> 16);
}

// pack 2 floats -> 2 bf16 in one u32 (v_cvt_pk_bf16_f32, RNE)
__device__ __forceinline__ unsigned pk2(float a, float b) {
    union { __hip_bfloat162 h; unsigned u; } v;
    v.h = __float22bfloat162_rn(float2{a, b});
    return v.u;
}

// raw 2^x (single v_exp_f32)
__device__ __forceinline__ float fexp2(float x) {
    float r;
    asm("v_exp_f32 %0, %1" : "=v"(r) : "v"(x));
    return r;
}

// async 16B global -> LDS (dest = wave-uniform base + lane*16)
__device__ __forceinline__ void gload16(const void* g, void* l) {
    __builtin_amdgcn_global_load_lds(
        (const __attribute__((address_space(1))) void*)g,
        (__attribute__((address_space(3))) void*)l, 16, 0, 0);
}

#define MEMFENCE() asm volatile("" ::: "memory")
#define WAITV6()  asm volatile("s_waitcnt vmcnt(6)" ::: "memory")
#define WAITV4()  asm volatile("s_waitcnt vmcnt(4)" ::: "memory")
#define WAITV0()  asm volatile("s_waitcnt vmcnt(0)" ::: "memory")
#define WAITLGKM() asm volatile("s_waitcnt lgkmcnt(0)" ::: "memory")

// Fused fp32->bf16 conversion of X and the 4 weight matrices in one dispatch.
__global__ __launch_bounds__(256) void convert_all(const float* __restrict__ X,
                                                   const float* __restrict__ Wq, const float* __restrict__ Wk,
                                                   const float* __restrict__ Wv, const float* __restrict__ Wo,
                                                   unsigned short* __restrict__ Xb,
                                                   unsigned short* __restrict__ Wqb, unsigned short* __restrict__ Wkb,
                                                   unsigned short* __restrict__ Wvb, unsigned short* __restrict__ Wob) {
    const int id = blockIdx.x;
    const float* src;
    unsigned short* dst;
    int i;
    if (id < 6144) {
        src = X; dst = Xb;
        i = id * 256 + threadIdx.x;
    } else {
        const int y = (id - 6144) / 576;
        src = (y == 0) ? Wq : (y == 1) ? Wk : (y == 2) ? Wv : Wo;
        dst = (y == 0) ? Wqb : (y == 1) ? Wkb : (y == 2) ? Wvb : Wob;
        i = ((id - 6144) % 576) * 256 + threadIdx.x;
    }
    float4 v = reinterpret_cast<const float4*>(src)[i];
    ushort4 o;
    o.x = f2b(v.x); o.y = f2b(v.y); o.z = f2b(v.z); o.w = f2b(v.w);
    reinterpret_cast<ushort4*>(dst)[i] = o;
}

// Fused Q/K/V projection (R7/R9-exact, measured 48.3us): 128x128 tile,
// 256 threads, BK=32, 3-buffer depth-2 ring, counted vmcnt(4), setprio.
// 48KB LDS -> 3 blocks/CU. Grid 1152 (64 by x 18 bx).
#define QKV_STAGE(t, b)                                                        \
    {                                                                          \
        const int k0 = (t) * 32;                                               \
        gload16(gAsrc[0] + k0, lAdst[0] + (b) * 4096);                         \
        gload16(gAsrc[1] + k0, lAdst[1] + (b) * 4096);                         \
        gload16(gWsrc[0] + k0, lWdst[0] + (b) * 4096);                         \
        gload16(gWsrc[1] + k0, lWdst[1] + (b) * 4096);                         \
    }

#define QKV_COMP(b)                                                            \
    {                                                                          \
        const unsigned short* Ab = &As[b][0];                                  \
        const unsigned short* Wb = &Ws[b][0];                                  \
        short8 bf[4];                                                          \
        _Pragma("unroll") for (int j = 0; j < 4; j++)                          \
            bf[j] = *(const short8*)&Wb[woff[j]];                              \
        __builtin_amdgcn_s_setprio(1);                                         \
        _Pragma("unroll") for (int i = 0; i < 4; i++) {                        \
            short8 af = *(const short8*)&Ab[aoff[i]];                          \
            _Pragma("unroll") for (int j = 0; j < 4; j++)                      \
                acc[i][j] = __builtin_amdgcn_mfma_f32_16x16x32_bf16(           \
                    af, bf[j], acc[i][j], 0, 0, 0);                            \
        }                                                                      \
        __builtin_amdgcn_s_setprio(0);                                         \
    }

__global__ __launch_bounds__(256, 3) void gemm_qkv(const unsigned short* __restrict__ A,
                                                   const unsigned short* __restrict__ Wq,
                                                   const unsigned short* __restrict__ Wk,
                                                   const unsigned short* __restrict__ Wv,
                                                   const float* __restrict__ bq,
                                                   const float* __restrict__ bk,
                                                   const float* __restrict__ bv,
                                                   unsigned short* __restrict__ Qh,
                                                   unsigned short* __restrict__ Kh,
                                                   unsigned short* __restrict__ Vt) {
    __shared__ __align__(16) unsigned short As[3][128 * 32];  // 24 KB
    __shared__ __align__(16) unsigned short Ws[3][128 * 32];  // 24 KB
    const int id = blockIdx.x;
    const int by = id & 63;
    const int bx = id >> 6;
    const int mat = bx / 6;
    const int m0 = by * 128;
    const int n0 = (bx % 6) * 128;
    const unsigned short* W = (mat == 0) ? Wq : (mat == 1) ? Wk : Wv;
    const float* bias = (mat == 0) ? bq : (mat == 1) ? bk : bv;
    unsigned short* Cout = (mat == 0) ? Qh : (mat == 1) ? Kh : Vt;

    const int tid = threadIdx.x;
    const int w = tid >> 6, l = tid & 63, quad = l >> 4, mr = l & 15;
    const int wm = (w >> 1) * 64, wn = (w & 1) * 64;

    // staging: 512 16B-units per matrix (128 rows x 4 units)
    const unsigned short* gAsrc[2];
    const unsigned short* gWsrc[2];
    unsigned short* lAdst[2];
    unsigned short* lWdst[2];
#pragma unroll
    for (int j = 0; j < 2; j++) {
        const int u = tid + j * 256;
        const int r = u >> 2, c = u & 3;
        const int cp = c ^ ((r >> 1) & 3);
        gAsrc[j] = &A[(size_t)(m0 + r) * Dn + cp * 8];
        gWsrc[j] = &W[(size_t)(n0 + r) * Dn + cp * 8];
        lAdst[j] = &As[0][u * 8];
        lWdst[j] = &Ws[0][u * 8];
    }

    // loop-invariant fragment LDS offsets (elems)
    int aoff[4], woff[4];
#pragma unroll
    for (int i = 0; i < 4; i++) {
        const int ra = wm + i * 16 + mr;
        aoff[i] = (ra * 4 + (quad ^ ((ra >> 1) & 3))) * 8;
    }
#pragma unroll
    for (int j = 0; j < 4; j++) {
        const int rw = wn + j * 16 + mr;
        woff[j] = (rw * 4 + (quad ^ ((rw >> 1) & 3))) * 8;
    }

    floatx4 acc[4][4];
#pragma unroll
    for (int i = 0; i < 4; i++)
#pragma unroll
        for (int j = 0; j < 4; j++) {
            floatx4 z = {0.f, 0.f, 0.f, 0.f};
            acc[i][j] = z;
        }

    // prologue: tiles 0,1 in flight (8 loads)
    QKV_STAGE(0, 0);
    QKV_STAGE(1, 1);

    // main: computes tiles 0..20, staging tiles 2..22 two phases ahead
    for (int t = 0; t < 21; t += 3) {
        WAITV4();  // tile t done; tile t+1 may remain in flight
        __builtin_amdgcn_s_barrier();
        MEMFENCE();
        QKV_STAGE(t + 2, 2);
        QKV_COMP(0);

        WAITV4();
        __builtin_amdgcn_s_barrier();
        MEMFENCE();
        QKV_STAGE(t + 3, 0);
        QKV_COMP(1);

        WAITV4();
        __builtin_amdgcn_s_barrier();
        MEMFENCE();
        QKV_STAGE(t + 4, 1);
        QKV_COMP(2);
    }
    // tail: tiles 21 (buf0), 22 (buf1), 23 (buf2)
    WAITV4();
    __builtin_amdgcn_s_barrier();
    MEMFENCE();
    QKV_STAGE(23, 2);
    QKV_COMP(0);

    WAITV4();
    __builtin_amdgcn_s_barrier();
    MEMFENCE();
    QKV_COMP(1);

    WAITV0();
    __builtin_amdgcn_s_barrier();
    MEMFENCE();
    QKV_COMP(2);

    // epilogue: Q/K scalar stores (lanes sweep contiguous d); V packed ushort4.
#pragma unroll
    for (int j = 0; j < 4; j++) {
        const int col = n0 + wn + j * 16 + mr;
        const float bval = bias[col];
        const int h = col >> 6, d = col & 63;
#pragma unroll
        for (int i = 0; i < 4; i++) {
            const int mbase = m0 + wm + i * 16 + quad * 4;
            const int b = mbase >> 10, s0 = mbase & 1023;
            const size_t base = (size_t)(b * Hn + h) << 16;
            if (mat == 2) {
                ushort4 o;
                o.x = f2b(acc[i][j][0] + bval);
                o.y = f2b(acc[i][j][1] + bval);
                o.z = f2b(acc[i][j][2] + bval);
                o.w = f2b(acc[i][j][3] + bval);
                *reinterpret_cast<ushort4*>(&Cout[base + (size_t)d * 1024 + s0]) = o;
            } else {
#pragma unroll
                for (int r = 0; r < 4; r++) {
                    const float val = acc[i][j][r] + bval;
                    Cout[base + (size_t)(s0 + r) * 64 + d] = f2b(val);
                }
            }
        }
    }
}

// O-projection + residual (R7-exact, part of best 212.3 bundle): 64x128 tile,
// BK=64, double-buffered counted-vmcnt staging.
#define OUT_COMPUTE(Ab, Wb)                                                    \
    {                                                                          \
        short8 af[4][2], bf[2][2];                                             \
        _Pragma("unroll") for (int i = 0; i < 4; i++)                          \
            _Pragma("unroll") for (int ks = 0; ks < 2; ks++)                   \
                af[i][ks] = *(const short8*)&(Ab)[aoff[i][ks]];                \
        _Pragma("unroll") for (int j = 0; j < 2; j++)                          \
            _Pragma("unroll") for (int ks = 0; ks < 2; ks++)                   \
                bf[j][ks] = *(const short8*)&(Wb)[woff[j][ks]];                \
        __builtin_amdgcn_s_setprio(1);                                         \
        _Pragma("unroll") for (int ks = 0; ks < 2; ks++)                       \
            _Pragma("unroll") for (int i = 0; i < 4; i++)                      \
                _Pragma("unroll") for (int j = 0; j < 2; j++)                  \
                    acc[i][j] = __builtin_amdgcn_mfma_f32_16x16x32_bf16(       \
                        af[i][ks], bf[j][ks], acc[i][j], 0, 0, 0);             \
        __builtin_amdgcn_s_setprio(0);                                         \
    }

__global__ __launch_bounds__(256) void gemm_out(const unsigned short* __restrict__ A,
                                                const unsigned short* __restrict__ W,
                                                const float* __restrict__ bias,
                                                const float* __restrict__ X,
                                                float* __restrict__ xres) {
    __shared__ __align__(16) unsigned short As[2][64 * 64];
    __shared__ __align__(16) unsigned short Ws[2][128 * 64];
    const int id = blockIdx.x;
    const int by = id & 127;
    const int bx = id >> 7;
    const int m0 = by * 64;
    const int n0 = bx * 128;

    const int tid = threadIdx.x;
    const int w = tid >> 6, l = tid & 63, quad = l >> 4, mr = l & 15;

    const unsigned short* gAsrc[2];
    unsigned short* lAdst[2];
#pragma unroll
    for (int j = 0; j < 2; j++) {
        const int u = tid + j * 256;
        const int r = u >> 3, c = u & 7;
        gAsrc[j] = &A[(size_t)(m0 + r) * Dn + (c ^ (r & 7)) * 8];
        lAdst[j] = &As[0][u * 8];
    }
    const unsigned short* gWsrc[4];
    unsigned short* lWdst[4];
#pragma unroll
    for (int j = 0; j < 4; j++) {
        const int u = tid + j * 256;
        const int r = u >> 3, c = u & 7;
        gWsrc[j] = &W[(size_t)(n0 + r) * Dn + (c ^ (r & 7)) * 8];
        lWdst[j] = &Ws[0][u * 8];
    }

    int aoff[4][2], woff[2][2];
#pragma unroll
    for (int i = 0; i < 4; i++) {
        const int ra = i * 16 + mr;
#pragma unroll
        for (int ks = 0; ks < 2; ks++)
            aoff[i][ks] = (ra * 8 + ((quad + ks * 4) ^ (ra & 7))) * 8;
    }
#pragma unroll
    for (int j = 0; j < 2; j++) {
        const int rw = w * 32 + j * 16 + mr;
#pragma unroll
        for (int ks = 0; ks < 2; ks++)
            woff[j][ks] = (rw * 8 + ((quad + ks * 4) ^ (rw & 7))) * 8;
    }

    floatx4 acc[4][2];
#pragma unroll
    for (int i = 0; i < 4; i++)
#pragma unroll
        for (int j = 0; j < 2; j++) {
            floatx4 z = {0.f, 0.f, 0.f, 0.f};
            acc[i][j] = z;
        }

    const unsigned short* Af = &As[0][0];
    const unsigned short* Wf = &Ws[0][0];

    // prologue: tile 0 -> buf0 (6 vmem instrs/wave)
#pragma unroll
    for (int j = 0; j < 2; j++) gload16(gAsrc[j], lAdst[j]);
#pragma unroll
    for (int j = 0; j < 4; j++) gload16(gWsrc[j], lWdst[j]);

    for (int kt = 0; kt < 12; kt += 2) {
        {
            const int k0 = (kt + 1) * 64;
#pragma unroll
            for (int j = 0; j < 2; j++) gload16(gAsrc[j] + k0, lAdst[j] + 4096);
#pragma unroll
            for (int j = 0; j < 4; j++) gload16(gWsrc[j] + k0, lWdst[j] + 8192);
        }
        WAITV6();
        __builtin_amdgcn_s_barrier();
        MEMFENCE();
        OUT_COMPUTE(Af, Wf);
        __builtin_amdgcn_s_barrier();
        MEMFENCE();

        if (kt + 2 < 12) {
            const int k0 = (kt + 2) * 64;
#pragma unroll
            for (int j = 0; j < 2; j++) gload16(gAsrc[j] + k0, lAdst[j]);
#pragma unroll
            for (int j = 0; j < 4; j++) gload16(gWsrc[j] + k0, lWdst[j]);
            WAITV6();
        } else {
            WAITV0();
        }
        __builtin_amdgcn_s_barrier();
        MEMFENCE();
        OUT_COMPUTE(Af + 4096, Wf + 8192);
        __builtin_amdgcn_s_barrier();
        MEMFENCE();
    }

#pragma unroll
    for (int j = 0; j < 2; j++) {
        const int col = n0 + w * 32 + j * 16 + mr;
        const float bval = bias[col];
#pragma unroll
        for (int i = 0; i < 4; i++) {
#pragma unroll
            for (int r = 0; r < 4; r++) {
                const int m = m0 + i * 16 + quad * 4 + r;
                xres[(size_t)m * Dn + col] = acc[i][j][r] + bval + X[(size_t)m * Dn + col];
            }
        }
    }
}

// Flash attention, round-10: drop Vs staging (V fragments read directly from
// L2-resident Vt; issued after QK^T so softmax covers the L2 latency) and
// drop msk LDS (k is lane-local in the swapped layout -> per-lane floatx4
// mask loads, issued before QK^T). Removes ~13 LDS ops/iter + the divergent
// tid<64 write. Ks/Ps/barrier structure unchanged (measured good).
__global__ __launch_bounds__(256) void flash_attn_mfma(const unsigned short* __restrict__ Qh,
                                                       const unsigned short* __restrict__ Kh,
                                                       const unsigned short* __restrict__ Vt,
                                                       const float* __restrict__ mask,
                                                       const float* __restrict__ head_mask,
                                                       unsigned short* __restrict__ ctx) {
    __shared__ __align__(16) unsigned short Ks[64 * 72];
    __shared__ __align__(16) unsigned short Ps[128 * 72];

    const float LOG2E = 1.44269504088896f;
    const float C1 = 0.125f * 1.44269504088896f;  // scale * log2e

    const int id = blockIdx.x;
    const int bh = id % 96;
    const int qt = id / 96;
    const int b = bh / Hn, h = bh % Hn;
    const int q0 = qt * 128;
    const int tid = threadIdx.x;
    const int w = tid >> 6, l = tid & 63, quad = l >> 4, mr = l & 15;
    const size_t hb = (size_t)(b * Hn + h) << 16;

    // Q fragments (B operand of swapped QK^T): q = q0 + w*32 + j*16 + mr
    short8 aq[2][2];
#pragma unroll
    for (int j = 0; j < 2; j++)
#pragma unroll
        for (int ks = 0; ks < 2; ks++)
            aq[j][ks] = *(const short8*)&Qh[hb + (size_t)(q0 + w * 32 + j * 16 + mr) * 64 + ks * 32 + quad * 8];

    float l_s[2] = {0.f, 0.f};
    floatx4 oacc[2][4];
#pragma unroll
    for (int i = 0; i < 2; i++)
#pragma unroll
        for (int jj = 0; jj < 4; jj++) {
            floatx4 z = {0.f, 0.f, 0.f, 0.f};
            oacc[i][jj] = z;
        }

    const int srow = tid >> 2;
    const int scol = (tid & 3) * 16;

    short8 pk0 = *(const short8*)&Kh[hb + (size_t)srow * 64 + scol];
    short8 pk1 = *(const short8*)&Kh[hb + (size_t)srow * 64 + scol + 8];

    for (int kt = 0; kt < Sn / 64; kt++) {
        const int k0 = kt * 64;
        __builtin_amdgcn_s_barrier();  // prev iter's Ks reads retired before overwrite
        MEMFENCE();
        *(short8*)&Ks[srow * 72 + scol] = pk0;
        *(short8*)&Ks[srow * 72 + scol + 8] = pk1;
        if (kt < Sn / 64 - 1) {
            pk0 = *(const short8*)&Kh[hb + (size_t)(k0 + 64 + srow) * 64 + scol];
            pk1 = *(const short8*)&Kh[hb + (size_t)(k0 + 64 + srow) * 64 + scol + 8];
        }
        // per-lane mask values (k = i*16 + quad*4 + r is lane-local), premult log2e;
        // issued here so QK^T covers the L2 latency
        floatx4 mkv[4];
#pragma unroll
        for (int i = 0; i < 4; i++) {
            floatx4 t = *(const floatx4*)&mask[b * Sn + k0 + i * 16 + quad * 4];
            mkv[i] = t * LOG2E;
        }
        WAITLGKM();  // own ds_writes visible; global prefetch stays in flight
        __builtin_amdgcn_s_barrier();
        MEMFENCE();

        // swapped QK^T: sacc[i][j] = S[k = i*16+quad*4+r][q = w*32+j*16+mr]
        floatx4 sacc[4][2];
#pragma unroll
        for (int i = 0; i < 4; i++)
#pragma unroll
            for (int j = 0; j < 2; j++) {
                floatx4 z = {0.f, 0.f, 0.f, 0.f};
                sacc[i][j] = z;
            }
#pragma unroll
        for (int ks = 0; ks < 2; ks++) {
            short8 kfr[4];
#pragma unroll
            for (int i = 0; i < 4; i++)
                kfr[i] = *(const short8*)&Ks[(i * 16 + mr) * 72 + ks * 32 + quad * 8];
            __builtin_amdgcn_s_setprio(1);
#pragma unroll
            for (int i = 0; i < 4; i++)
#pragma unroll
                for (int j = 0; j < 2; j++)
                    sacc[i][j] = __builtin_amdgcn_mfma_f32_16x16x32_bf16(kfr[i], aq[j][ks], sacc[i][j], 0, 0, 0);
            __builtin_amdgcn_s_setprio(0);
        }

        // V fragments direct from global (L2-resident; latency hides under softmax)
        short8 bvv[2][4];
#pragma unroll
        for (int ks = 0; ks < 2; ks++)
#pragma unroll
            for (int jj = 0; jj < 4; jj++)
                bvv[ks][jj] = *(const short8*)&Vt[hb + (size_t)(jj * 16 + mr) * 1024 + k0 + ks * 32 + quad * 8];

        // softmax: p = 2^(s*C1 + mk); packed bf16 P-writes (k-contiguous along r)
#pragma unroll
        for (int i = 0; i < 4; i++) {
#pragma unroll
            for (int j = 0; j < 2; j++) {
                float p[4];
#pragma unroll
                for (int r = 0; r < 4; r++) {
                    p[r] = fexp2(sacc[i][j][r] * C1 + mkv[i][r]);
                    l_s[j] += p[r];
                }
                uint2 w2;
                w2.x = pk2(p[0], p[1]);
                w2.y = pk2(p[2], p[3]);
                *(uint2*)&Ps[(w * 32 + j * 16 + mr) * 72 + i * 16 + quad * 4] = w2;
            }
        }

        // PV: ap from Ps (wave-private), bv from registers
#pragma unroll
        for (int ks = 0; ks < 2; ks++) {
            short8 ap0 = *(const short8*)&Ps[(w * 32 + mr) * 72 + ks * 32 + quad * 8];
            short8 ap1 = *(const short8*)&Ps[(w * 32 + 16 + mr) * 72 + ks * 32 + quad * 8];
            __builtin_amdgcn_s_setprio(1);
#pragma unroll
            for (int jj = 0; jj < 4; jj++) {
                oacc[0][jj] = __builtin_amdgcn_mfma_f32_16x16x32_bf16(ap0, bvv[ks][jj], oacc[0][jj], 0, 0, 0);
                oacc[1][jj] = __builtin_amdgcn_mfma_f32_16x16x32_bf16(ap1, bvv[ks][jj], oacc[1][jj], 0, 0, 0);
            }
            __builtin_amdgcn_s_setprio(0);
        }
    }

    // reduce l_s across quads (lanes sharing mr), then redistribute to oacc rows
    float L[2];
#pragma unroll
    for (int j = 0; j < 2; j++) {
        float t = l_s[j];
        t += __shfl_xor(t, 16);
        t += __shfl_xor(t, 32);
        L[j] = t;
    }
    const float hm = head_mask[h];
    float inv[2][4];
#pragma unroll
    for (int i = 0; i < 2; i++)
#pragma unroll
        for (int r = 0; r < 4; r++)
            inv[i][r] = hm / __shfl(L[i], quad * 4 + r);

#pragma unroll
    for (int i = 0; i < 2; i++)
#pragma unroll
        for (int jj = 0; jj < 4; jj++)
#pragma unroll
            for (int r = 0; r < 4; r++) {
                const int qrow = q0 + w * 32 + i * 16 + quad * 4 + r;
                ctx[(size_t)(b * Sn + qrow) * Dn + h * 64 + jj * 16 + mr] = f2b(oacc[i][jj][r] * inv[i][r]);
            }
}

// LayerNorm, shuffle-based reduction (1 barrier), one block per row of 768
__global__ __launch_bounds__(256) void ln_kernel(const float* __restrict__ x,
                                                 const float* __restrict__ gamma,
                                                 const float* __restrict__ beta,
                                                 float* __restrict__ out) {
    __shared__ float r1[4];
    __shared__ float r2[4];
    const int m = blockIdx.x;
    const int tid = threadIdx.x;
    const int w = tid >> 6, lane = tid & 63;

    float xv[3];
    float s = 0.f, ss = 0.f;
#pragma unroll
    for (int i = 0; i < 3; i++) {
        int j = tid + i * 256;
        float t = x[(size_t)m * Dn + j];
        xv[i] = t;
        s += t;
        ss += t * t;
    }
#pragma unroll
    for (int o = 1; o < 64; o <<= 1) {
        s += __shfl_xor(s, o);
        ss += __shfl_xor(ss, o);
    }
    if (lane == 0) { r1[w] = s; r2[w] = ss; }
    __syncthreads();
    const float sum = r1[0] + r1[1] + r1[2] + r1[3];
    const float sqs = r2[0] + r2[1] + r2[2] + r2[3];
    const float mu = sum * (1.0f / Dn);
    const float var = sqs * (1.0f / Dn) - mu * mu;
    const float rstd = rsqrtf(var + 1e-12f);
#pragma unroll
    for (int i = 0; i < 3; i++) {
        int j = tid + i * 256;
        out[(size_t)m * Dn + j] = (xv[i] - mu) * rstd * gamma[j] + beta[j];
    }
}

extern "C" void kernel_launch(void* const* d_in, const int* in_sizes, int n_in,
                              void* d_out, int out_size, void* d_ws, size_t ws_size,
                              hipStream_t stream) {
    const float* X         = (const float*)d_in[0];
    const float* mask      = (const float*)d_in[1];
    const float* head_mask = (const float*)d_in[2];
    const float* Wq        = (const float*)d_in[3];
    const float* bq        = (const float*)d_in[4];
    const float* Wk        = (const float*)d_in[5];
    const float* bk        = (const float*)d_in[6];
    const float* Wv        = (const float*)d_in[7];
    const float* bv        = (const float*)d_in[8];
    const float* Wo        = (const float*)d_in[9];
    const float* bo        = (const float*)d_in[10];
    const float* gamma     = (const float*)d_in[11];
    const float* beta      = (const float*)d_in[12];
    float* out = (float*)d_out;

    const size_t NE = (size_t)Bn * Sn * Dn;   // 6291456
    const size_t NW = (size_t)Dn * Dn;        // 589824

    char* p = (char*)d_ws;
    unsigned short* Xb  = (unsigned short*)p;  p += NE * 2;
    unsigned short* Wqb = (unsigned short*)p;  p += NW * 2;
    unsigned short* Wkb = (unsigned short*)p;  p += NW * 2;
    unsigned short* Wvb = (unsigned short*)p;  p += NW * 2;
    unsigned short* Wob = (unsigned short*)p;  p += NW * 2;
    unsigned short* Qh  = (unsigned short*)p;  p += NE * 2;
    unsigned short* Kh  = (unsigned short*)p;  p += NE * 2;
    unsigned short* Vtb = (unsigned short*)p;  p += NE * 2;
    unsigned short* ctx = (unsigned short*)p;  p += NE * 2;
    float* xres = (float*)p;

    convert_all<<<8448, 256, 0, stream>>>(X, Wq, Wk, Wv, Wo, Xb, Wqb, Wkb, Wvb, Wob);

    gemm_qkv<<<1152, 256, 0, stream>>>(Xb, Wqb, Wkb, Wvb, bq, bk, bv, Qh, Kh, Vtb);

    flash_attn_mfma<<<768, 256, 0, stream>>>(Qh, Kh, Vtb, mask, head_mask, ctx);

    gemm_out<<<768, 256, 0, stream>>>(ctx, Wob, bo, X, xres);

    ln_kernel<<<MROWS, 256, 0, stream>>>(xres, gamma, beta, out);
}

// Round 11
// 210.684 us; speedup vs baseline: 1.1869x; 1.1869x over previous
//
#include <hip/hip_runtime.h>
#include <hip/hip_bf16.h>
#include <math.h>

#define Bn 8
#define Sn 1024
#define Dn 768
#define Hn 12
#define MROWS (Bn * Sn)

typedef __attribute__((ext_vector_type(8))) short short8;
typedef __attribute__((ext_vector_type(4))) float floatx4;

__device__ __forceinline__ unsigned short f2b(float x) {
    union { float f; unsigned u; } v; v.f = x;
    unsigned r = v.u + 0x7fffu + ((v.u >> 16) & 1u);
    return (unsigned short)(r >> 16);
}

// pack 2 floats -> 2 bf16 in one u32 (v_cvt_pk_bf16_f32, RNE)
__device__ __forceinline__ unsigned pk2(float a, float b) {
    union { __hip_bfloat162 h; unsigned u; } v;
    v.h = __float22bfloat162_rn(float2{a, b});
    return v.u;
}

// raw 2^x (single v_exp_f32)
__device__ __forceinline__ float fexp2(float x) {
    float r;
    asm("v_exp_f32 %0, %1" : "=v"(r) : "v"(x));
    return r;
}

// async 16B global -> LDS (dest = wave-uniform base + lane*16)
__device__ __forceinline__ void gload16(const void* g, void* l) {
    __builtin_amdgcn_global_load_lds(
        (const __attribute__((address_space(1))) void*)g,
        (__attribute__((address_space(3))) void*)l, 16, 0, 0);
}

#define MEMFENCE() asm volatile("" ::: "memory")
#define WAITV6()  asm volatile("s_waitcnt vmcnt(6)" ::: "memory")
#define WAITV4()  asm volatile("s_waitcnt vmcnt(4)" ::: "memory")
#define WAITV0()  asm volatile("s_waitcnt vmcnt(0)" ::: "memory")
#define WAITLGKM() asm volatile("s_waitcnt lgkmcnt(0)" ::: "memory")

// Fused fp32->bf16 conversion of X and the 4 weight matrices in one dispatch.
__global__ __launch_bounds__(256) void convert_all(const float* __restrict__ X,
                                                   const float* __restrict__ Wq, const float* __restrict__ Wk,
                                                   const float* __restrict__ Wv, const float* __restrict__ Wo,
                                                   unsigned short* __restrict__ Xb,
                                                   unsigned short* __restrict__ Wqb, unsigned short* __restrict__ Wkb,
                                                   unsigned short* __restrict__ Wvb, unsigned short* __restrict__ Wob) {
    const int id = blockIdx.x;
    const float* src;
    unsigned short* dst;
    int i;
    if (id < 6144) {
        src = X; dst = Xb;
        i = id * 256 + threadIdx.x;
    } else {
        const int y = (id - 6144) / 576;
        src = (y == 0) ? Wq : (y == 1) ? Wk : (y == 2) ? Wv : Wo;
        dst = (y == 0) ? Wqb : (y == 1) ? Wkb : (y == 2) ? Wvb : Wob;
        i = ((id - 6144) % 576) * 256 + threadIdx.x;
    }
    float4 v = reinterpret_cast<const float4*>(src)[i];
    ushort4 o;
    o.x = f2b(v.x); o.y = f2b(v.y); o.z = f2b(v.z); o.w = f2b(v.w);
    reinterpret_cast<ushort4*>(dst)[i] = o;
}

// Fused Q/K/V projection (R7/R9-exact, measured 48.3us): 128x128 tile,
// 256 threads, BK=32, 3-buffer depth-2 ring, counted vmcnt(4), setprio.
// 48KB LDS -> 3 blocks/CU. Grid 1152 (64 by x 18 bx).
#define QKV_STAGE(t, b)                                                        \
    {                                                                          \
        const int k0 = (t) * 32;                                               \
        gload16(gAsrc[0] + k0, lAdst[0] + (b) * 4096);                         \
        gload16(gAsrc[1] + k0, lAdst[1] + (b) * 4096);                         \
        gload16(gWsrc[0] + k0, lWdst[0] + (b) * 4096);                         \
        gload16(gWsrc[1] + k0, lWdst[1] + (b) * 4096);                         \
    }

#define QKV_COMP(b)                                                            \
    {                                                                          \
        const unsigned short* Ab = &As[b][0];                                  \
        const unsigned short* Wb = &Ws[b][0];                                  \
        short8 bf[4];                                                          \
        _Pragma("unroll") for (int j = 0; j < 4; j++)                          \
            bf[j] = *(const short8*)&Wb[woff[j]];                              \
        __builtin_amdgcn_s_setprio(1);                                         \
        _Pragma("unroll") for (int i = 0; i < 4; i++) {                        \
            short8 af = *(const short8*)&Ab[aoff[i]];                          \
            _Pragma("unroll") for (int j = 0; j < 4; j++)                      \
                acc[i][j] = __builtin_amdgcn_mfma_f32_16x16x32_bf16(           \
                    af, bf[j], acc[i][j], 0, 0, 0);                            \
        }                                                                      \
        __builtin_amdgcn_s_setprio(0);                                         \
    }

__global__ __launch_bounds__(256, 3) void gemm_qkv(const unsigned short* __restrict__ A,
                                                   const unsigned short* __restrict__ Wq,
                                                   const unsigned short* __restrict__ Wk,
                                                   const unsigned short* __restrict__ Wv,
                                                   const float* __restrict__ bq,
                                                   const float* __restrict__ bk,
                                                   const float* __restrict__ bv,
                                                   unsigned short* __restrict__ Qh,
                                                   unsigned short* __restrict__ Kh,
                                                   unsigned short* __restrict__ Vt) {
    __shared__ __align__(16) unsigned short As[3][128 * 32];  // 24 KB
    __shared__ __align__(16) unsigned short Ws[3][128 * 32];  // 24 KB
    const int id = blockIdx.x;
    const int by = id & 63;
    const int bx = id >> 6;
    const int mat = bx / 6;
    const int m0 = by * 128;
    const int n0 = (bx % 6) * 128;
    const unsigned short* W = (mat == 0) ? Wq : (mat == 1) ? Wk : Wv;
    const float* bias = (mat == 0) ? bq : (mat == 1) ? bk : bv;
    unsigned short* Cout = (mat == 0) ? Qh : (mat == 1) ? Kh : Vt;

    const int tid = threadIdx.x;
    const int w = tid >> 6, l = tid & 63, quad = l >> 4, mr = l & 15;
    const int wm = (w >> 1) * 64, wn = (w & 1) * 64;

    // staging: 512 16B-units per matrix (128 rows x 4 units)
    const unsigned short* gAsrc[2];
    const unsigned short* gWsrc[2];
    unsigned short* lAdst[2];
    unsigned short* lWdst[2];
#pragma unroll
    for (int j = 0; j < 2; j++) {
        const int u = tid + j * 256;
        const int r = u >> 2, c = u & 3;
        const int cp = c ^ ((r >> 1) & 3);
        gAsrc[j] = &A[(size_t)(m0 + r) * Dn + cp * 8];
        gWsrc[j] = &W[(size_t)(n0 + r) * Dn + cp * 8];
        lAdst[j] = &As[0][u * 8];
        lWdst[j] = &Ws[0][u * 8];
    }

    // loop-invariant fragment LDS offsets (elems)
    int aoff[4], woff[4];
#pragma unroll
    for (int i = 0; i < 4; i++) {
        const int ra = wm + i * 16 + mr;
        aoff[i] = (ra * 4 + (quad ^ ((ra >> 1) & 3))) * 8;
    }
#pragma unroll
    for (int j = 0; j < 4; j++) {
        const int rw = wn + j * 16 + mr;
        woff[j] = (rw * 4 + (quad ^ ((rw >> 1) & 3))) * 8;
    }

    floatx4 acc[4][4];
#pragma unroll
    for (int i = 0; i < 4; i++)
#pragma unroll
        for (int j = 0; j < 4; j++) {
            floatx4 z = {0.f, 0.f, 0.f, 0.f};
            acc[i][j] = z;
        }

    // prologue: tiles 0,1 in flight (8 loads)
    QKV_STAGE(0, 0);
    QKV_STAGE(1, 1);

    // main: computes tiles 0..20, staging tiles 2..22 two phases ahead
    for (int t = 0; t < 21; t += 3) {
        WAITV4();  // tile t done; tile t+1 may remain in flight
        __builtin_amdgcn_s_barrier();
        MEMFENCE();
        QKV_STAGE(t + 2, 2);
        QKV_COMP(0);

        WAITV4();
        __builtin_amdgcn_s_barrier();
        MEMFENCE();
        QKV_STAGE(t + 3, 0);
        QKV_COMP(1);

        WAITV4();
        __builtin_amdgcn_s_barrier();
        MEMFENCE();
        QKV_STAGE(t + 4, 1);
        QKV_COMP(2);
    }
    // tail: tiles 21 (buf0), 22 (buf1), 23 (buf2)
    WAITV4();
    __builtin_amdgcn_s_barrier();
    MEMFENCE();
    QKV_STAGE(23, 2);
    QKV_COMP(0);

    WAITV4();
    __builtin_amdgcn_s_barrier();
    MEMFENCE();
    QKV_COMP(1);

    WAITV0();
    __builtin_amdgcn_s_barrier();
    MEMFENCE();
    QKV_COMP(2);

    // epilogue: Q/K scalar stores (lanes sweep contiguous d); V packed ushort4.
#pragma unroll
    for (int j = 0; j < 4; j++) {
        const int col = n0 + wn + j * 16 + mr;
        const float bval = bias[col];
        const int h = col >> 6, d = col & 63;
#pragma unroll
    for (int i = 0; i < 4; i++) {
            const int mbase = m0 + wm + i * 16 + quad * 4;
            const int b = mbase >> 10, s0 = mbase & 1023;
            const size_t base = (size_t)(b * Hn + h) << 16;
            if (mat == 2) {
                ushort4 o;
                o.x = f2b(acc[i][j][0] + bval);
                o.y = f2b(acc[i][j][1] + bval);
                o.z = f2b(acc[i][j][2] + bval);
                o.w = f2b(acc[i][j][3] + bval);
                *reinterpret_cast<ushort4*>(&Cout[base + (size_t)d * 1024 + s0]) = o;
            } else {
#pragma unroll
                for (int r = 0; r < 4; r++) {
                    const float val = acc[i][j][r] + bval;
                    Cout[base + (size_t)(s0 + r) * 64 + d] = f2b(val);
                }
            }
        }
    }
}

// O-projection + residual (R7-exact, part of best 212.3 bundle): 64x128 tile,
// BK=64, double-buffered counted-vmcnt staging.
#define OUT_COMPUTE(Ab, Wb)                                                    \
    {                                                                          \
        short8 af[4][2], bf[2][2];                                             \
        _Pragma("unroll") for (int i = 0; i < 4; i++)                          \
            _Pragma("unroll") for (int ks = 0; ks < 2; ks++)                   \
                af[i][ks] = *(const short8*)&(Ab)[aoff[i][ks]];                \
        _Pragma("unroll") for (int j = 0; j < 2; j++)                          \
            _Pragma("unroll") for (int ks = 0; ks < 2; ks++)                   \
                bf[j][ks] = *(const short8*)&(Wb)[woff[j][ks]];                \
        __builtin_amdgcn_s_setprio(1);                                         \
        _Pragma("unroll") for (int ks = 0; ks < 2; ks++)                       \
            _Pragma("unroll") for (int i = 0; i < 4; i++)                      \
                _Pragma("unroll") for (int j = 0; j < 2; j++)                  \
                    acc[i][j] = __builtin_amdgcn_mfma_f32_16x16x32_bf16(       \
                        af[i][ks], bf[j][ks], acc[i][j], 0, 0, 0);             \
        __builtin_amdgcn_s_setprio(0);                                         \
    }

__global__ __launch_bounds__(256) void gemm_out(const unsigned short* __restrict__ A,
                                                const unsigned short* __restrict__ W,
                                                const float* __restrict__ bias,
                                                const float* __restrict__ X,
                                                float* __restrict__ xres) {
    __shared__ __align__(16) unsigned short As[2][64 * 64];
    __shared__ __align__(16) unsigned short Ws[2][128 * 64];
    const int id = blockIdx.x;
    const int by = id & 127;
    const int bx = id >> 7;
    const int m0 = by * 64;
    const int n0 = bx * 128;

    const int tid = threadIdx.x;
    const int w = tid >> 6, l = tid & 63, quad = l >> 4, mr = l & 15;

    const unsigned short* gAsrc[2];
    unsigned short* lAdst[2];
#pragma unroll
    for (int j = 0; j < 2; j++) {
        const int u = tid + j * 256;
        const int r = u >> 3, c = u & 7;
        gAsrc[j] = &A[(size_t)(m0 + r) * Dn + (c ^ (r & 7)) * 8];
        lAdst[j] = &As[0][u * 8];
    }
    const unsigned short* gWsrc[4];
    unsigned short* lWdst[4];
#pragma unroll
    for (int j = 0; j < 4; j++) {
        const int u = tid + j * 256;
        const int r = u >> 3, c = u & 7;
        gWsrc[j] = &W[(size_t)(n0 + r) * Dn + (c ^ (r & 7)) * 8];
        lWdst[j] = &Ws[0][u * 8];
    }

    int aoff[4][2], woff[2][2];
#pragma unroll
    for (int i = 0; i < 4; i++) {
        const int ra = i * 16 + mr;
#pragma unroll
        for (int ks = 0; ks < 2; ks++)
            aoff[i][ks] = (ra * 8 + ((quad + ks * 4) ^ (ra & 7))) * 8;
    }
#pragma unroll
    for (int j = 0; j < 2; j++) {
        const int rw = w * 32 + j * 16 + mr;
#pragma unroll
        for (int ks = 0; ks < 2; ks++)
            woff[j][ks] = (rw * 8 + ((quad + ks * 4) ^ (rw & 7))) * 8;
    }

    floatx4 acc[4][2];
#pragma unroll
    for (int i = 0; i < 4; i++)
#pragma unroll
        for (int j = 0; j < 2; j++) {
            floatx4 z = {0.f, 0.f, 0.f, 0.f};
            acc[i][j] = z;
        }

    const unsigned short* Af = &As[0][0];
    const unsigned short* Wf = &Ws[0][0];

    // prologue: tile 0 -> buf0 (6 vmem instrs/wave)
#pragma unroll
    for (int j = 0; j < 2; j++) gload16(gAsrc[j], lAdst[j]);
#pragma unroll
    for (int j = 0; j < 4; j++) gload16(gWsrc[j], lWdst[j]);

    for (int kt = 0; kt < 12; kt += 2) {
        {
            const int k0 = (kt + 1) * 64;
#pragma unroll
            for (int j = 0; j < 2; j++) gload16(gAsrc[j] + k0, lAdst[j] + 4096);
#pragma unroll
            for (int j = 0; j < 4; j++) gload16(gWsrc[j] + k0, lWdst[j] + 8192);
        }
        WAITV6();
        __builtin_amdgcn_s_barrier();
        MEMFENCE();
        OUT_COMPUTE(Af, Wf);
        __builtin_amdgcn_s_barrier();
        MEMFENCE();

        if (kt + 2 < 12) {
            const int k0 = (kt + 2) * 64;
#pragma unroll
            for (int j = 0; j < 2; j++) gload16(gAsrc[j] + k0, lAdst[j]);
#pragma unroll
            for (int j = 0; j < 4; j++) gload16(gWsrc[j] + k0, lWdst[j]);
            WAITV6();
        } else {
            WAITV0();
        }
        __builtin_amdgcn_s_barrier();
        MEMFENCE();
        OUT_COMPUTE(Af + 4096, Wf + 8192);
        __builtin_amdgcn_s_barrier();
        MEMFENCE();
    }

#pragma unroll
    for (int j = 0; j < 2; j++) {
        const int col = n0 + w * 32 + j * 16 + mr;
        const float bval = bias[col];
#pragma unroll
        for (int i = 0; i < 4; i++) {
#pragma unroll
            for (int r = 0; r < 4; r++) {
                const int m = m0 + i * 16 + quad * 4 + r;
                xres[(size_t)m * Dn + col] = acc[i][j][r] + bval + X[(size_t)m * Dn + col];
            }
        }
    }
}

// Flash attention, round-11: R7 structure restored (Vs staging with COALESCED
// srow/scol register prefetch -- R10's direct-from-global V read was a
// 2KB-stride/lane pattern, 64 cache lines per load, and cost 2x). Single kept
// change from R10: mask in registers (per-lane floatx4, L1-broadcast within
// quads) instead of msk LDS + divergent tid<64 write.
__global__ __launch_bounds__(256) void flash_attn_mfma(const unsigned short* __restrict__ Qh,
                                                       const unsigned short* __restrict__ Kh,
                                                       const unsigned short* __restrict__ Vt,
                                                       const float* __restrict__ mask,
                                                       const float* __restrict__ head_mask,
                                                       unsigned short* __restrict__ ctx) {
    __shared__ __align__(16) unsigned short Ks[64 * 72];
    __shared__ __align__(16) unsigned short Vs[64 * 72];
    __shared__ __align__(16) unsigned short Ps[128 * 72];

    const float LOG2E = 1.44269504088896f;
    const float C1 = 0.125f * 1.44269504088896f;  // scale * log2e

    const int id = blockIdx.x;
    const int bh = id % 96;
    const int qt = id / 96;
    const int b = bh / Hn, h = bh % Hn;
    const int q0 = qt * 128;
    const int tid = threadIdx.x;
    const int w = tid >> 6, l = tid & 63, quad = l >> 4, mr = l & 15;
    const size_t hb = (size_t)(b * Hn + h) << 16;

    // Q fragments (B operand of swapped QK^T): q = q0 + w*32 + j*16 + mr
    short8 aq[2][2];
#pragma unroll
    for (int j = 0; j < 2; j++)
#pragma unroll
        for (int ks = 0; ks < 2; ks++)
            aq[j][ks] = *(const short8*)&Qh[hb + (size_t)(q0 + w * 32 + j * 16 + mr) * 64 + ks * 32 + quad * 8];

    float l_s[2] = {0.f, 0.f};
    floatx4 oacc[2][4];
#pragma unroll
    for (int i = 0; i < 2; i++)
#pragma unroll
        for (int jj = 0; jj < 4; jj++) {
            floatx4 z = {0.f, 0.f, 0.f, 0.f};
            oacc[i][jj] = z;
        }

    const int srow = tid >> 2;
    const int scol = (tid & 3) * 16;

    short8 pk0 = *(const short8*)&Kh[hb + (size_t)srow * 64 + scol];
    short8 pk1 = *(const short8*)&Kh[hb + (size_t)srow * 64 + scol + 8];
    short8 pv0 = *(const short8*)&Vt[hb + (size_t)srow * 1024 + scol];
    short8 pv1 = *(const short8*)&Vt[hb + (size_t)srow * 1024 + scol + 8];

    for (int kt = 0; kt < Sn / 64; kt++) {
        const int k0 = kt * 64;
        __builtin_amdgcn_s_barrier();  // prev iter's LDS reads retired before overwrite
        MEMFENCE();
        *(short8*)&Ks[srow * 72 + scol] = pk0;
        *(short8*)&Ks[srow * 72 + scol + 8] = pk1;
        *(short8*)&Vs[srow * 72 + scol] = pv0;
        *(short8*)&Vs[srow * 72 + scol + 8] = pv1;
        if (kt < Sn / 64 - 1) {
            pk0 = *(const short8*)&Kh[hb + (size_t)(k0 + 64 + srow) * 64 + scol];
            pk1 = *(const short8*)&Kh[hb + (size_t)(k0 + 64 + srow) * 64 + scol + 8];
            pv0 = *(const short8*)&Vt[hb + (size_t)srow * 1024 + k0 + 64 + scol];
            pv1 = *(const short8*)&Vt[hb + (size_t)srow * 1024 + k0 + 64 + scol + 8];
        }
        // per-lane mask (k = i*16 + quad*4 + r is lane-local); quad-broadcast L1 hits
        floatx4 mkv[4];
#pragma unroll
        for (int i = 0; i < 4; i++) {
            floatx4 t = *(const floatx4*)&mask[b * Sn + k0 + i * 16 + quad * 4];
            mkv[i] = t * LOG2E;
        }
        WAITLGKM();  // own ds_writes visible; global prefetch stays in flight
        __builtin_amdgcn_s_barrier();
        MEMFENCE();

        // swapped QK^T: sacc[i][j] = S[k = i*16+quad*4+r][q = w*32+j*16+mr]
        floatx4 sacc[4][2];
#pragma unroll
        for (int i = 0; i < 4; i++)
#pragma unroll
            for (int j = 0; j < 2; j++) {
                floatx4 z = {0.f, 0.f, 0.f, 0.f};
                sacc[i][j] = z;
            }
#pragma unroll
        for (int ks = 0; ks < 2; ks++) {
            short8 kfr[4];
#pragma unroll
            for (int i = 0; i < 4; i++)
                kfr[i] = *(const short8*)&Ks[(i * 16 + mr) * 72 + ks * 32 + quad * 8];
            __builtin_amdgcn_s_setprio(1);
#pragma unroll
            for (int i = 0; i < 4; i++)
#pragma unroll
                for (int j = 0; j < 2; j++)
                    sacc[i][j] = __builtin_amdgcn_mfma_f32_16x16x32_bf16(kfr[i], aq[j][ks], sacc[i][j], 0, 0, 0);
            __builtin_amdgcn_s_setprio(0);
        }

        // softmax: p = 2^(s*C1 + mk); packed bf16 P-writes (k-contiguous along r)
#pragma unroll
        for (int i = 0; i < 4; i++) {
#pragma unroll
            for (int j = 0; j < 2; j++) {
                float p[4];
#pragma unroll
                for (int r = 0; r < 4; r++) {
                    p[r] = fexp2(sacc[i][j][r] * C1 + mkv[i][r]);
                    l_s[j] += p[r];
                }
                uint2 w2;
                w2.x = pk2(p[0], p[1]);
                w2.y = pk2(p[2], p[3]);
                *(uint2*)&Ps[(w * 32 + j * 16 + mr) * 72 + i * 16 + quad * 4] = w2;
            }
        }

        // PV: wave-private P rows, V from LDS (coalesced-staged)
#pragma unroll
        for (int ks = 0; ks < 2; ks++) {
            short8 ap0 = *(const short8*)&Ps[(w * 32 + mr) * 72 + ks * 32 + quad * 8];
            short8 ap1 = *(const short8*)&Ps[(w * 32 + 16 + mr) * 72 + ks * 32 + quad * 8];
            __builtin_amdgcn_s_setprio(1);
#pragma unroll
            for (int jj = 0; jj < 4; jj++) {
                short8 bv = *(const short8*)&Vs[(jj * 16 + mr) * 72 + ks * 32 + quad * 8];
                oacc[0][jj] = __builtin_amdgcn_mfma_f32_16x16x32_bf16(ap0, bv, oacc[0][jj], 0, 0, 0);
                oacc[1][jj] = __builtin_amdgcn_mfma_f32_16x16x32_bf16(ap1, bv, oacc[1][jj], 0, 0, 0);
            }
            __builtin_amdgcn_s_setprio(0);
        }
    }

    // reduce l_s across quads (lanes sharing mr), then redistribute to oacc rows
    float L[2];
#pragma unroll
    for (int j = 0; j < 2; j++) {
        float t = l_s[j];
        t += __shfl_xor(t, 16);
        t += __shfl_xor(t, 32);
        L[j] = t;
    }
    const float hm = head_mask[h];
    float inv[2][4];
#pragma unroll
    for (int i = 0; i < 2; i++)
#pragma unroll
        for (int r = 0; r < 4; r++)
            inv[i][r] = hm / __shfl(L[i], quad * 4 + r);

#pragma unroll
    for (int i = 0; i < 2; i++)
#pragma unroll
        for (int jj = 0; jj < 4; jj++)
#pragma unroll
            for (int r = 0; r < 4; r++) {
                const int qrow = q0 + w * 32 + i * 16 + quad * 4 + r;
                ctx[(size_t)(b * Sn + qrow) * Dn + h * 64 + jj * 16 + mr] = f2b(oacc[i][jj][r] * inv[i][r]);
            }
}

// LayerNorm, shuffle-based reduction (1 barrier), one block per row of 768
__global__ __launch_bounds__(256) void ln_kernel(const float* __restrict__ x,
                                                 const float* __restrict__ gamma,
                                                 const float* __restrict__ beta,
                                                 float* __restrict__ out) {
    __shared__ float r1[4];
    __shared__ float r2[4];
    const int m = blockIdx.x;
    const int tid = threadIdx.x;
    const int w = tid >> 6, lane = tid & 63;

    float xv[3];
    float s = 0.f, ss = 0.f;
#pragma unroll
    for (int i = 0; i < 3; i++) {
        int j = tid + i * 256;
        float t = x[(size_t)m * Dn + j];
        xv[i] = t;
        s += t;
        ss += t * t;
    }
#pragma unroll
    for (int o = 1; o < 64; o <<= 1) {
        s += __shfl_xor(s, o);
        ss += __shfl_xor(ss, o);
    }
    if (lane == 0) { r1[w] = s; r2[w] = ss; }
    __syncthreads();
    const float sum = r1[0] + r1[1] + r1[2] + r1[3];
    const float sqs = r2[0] + r2[1] + r2[2] + r2[3];
    const float mu = sum * (1.0f / Dn);
    const float var = sqs * (1.0f / Dn) - mu * mu;
    const float rstd = rsqrtf(var + 1e-12f);
#pragma unroll
    for (int i = 0; i < 3; i++) {
        int j = tid + i * 256;
        out[(size_t)m * Dn + j] = (xv[i] - mu) * rstd * gamma[j] + beta[j];
    }
}

extern "C" void kernel_launch(void* const* d_in, const int* in_sizes, int n_in,
                              void* d_out, int out_size, void* d_ws, size_t ws_size,
                              hipStream_t stream) {
    const float* X         = (const float*)d_in[0];
    const float* mask      = (const float*)d_in[1];
    const float* head_mask = (const float*)d_in[2];
    const float* Wq        = (const float*)d_in[3];
    const float* bq        = (const float*)d_in[4];
    const float* Wk        = (const float*)d_in[5];
    const float* bk        = (const float*)d_in[6];
    const float* Wv        = (const float*)d_in[7];
    const float* bv        = (const float*)d_in[8];
    const float* Wo        = (const float*)d_in[9];
    const float* bo        = (const float*)d_in[10];
    const float* gamma     = (const float*)d_in[11];
    const float* beta      = (const float*)d_in[12];
    float* out = (float*)d_out;

    const size_t NE = (size_t)Bn * Sn * Dn;   // 6291456
    const size_t NW = (size_t)Dn * Dn;        // 589824

    char* p = (char*)d_ws;
    unsigned short* Xb  = (unsigned short*)p;  p += NE * 2;
    unsigned short* Wqb = (unsigned short*)p;  p += NW * 2;
    unsigned short* Wkb = (unsigned short*)p;  p += NW * 2;
    unsigned short* Wvb = (unsigned short*)p;  p += NW * 2;
    unsigned short* Wob = (unsigned short*)p;  p += NW * 2;
    unsigned short* Qh  = (unsigned short*)p;  p += NE * 2;
    unsigned short* Kh  = (unsigned short*)p;  p += NE * 2;
    unsigned short* Vtb = (unsigned short*)p;  p += NE * 2;
    unsigned short* ctx = (unsigned short*)p;  p += NE * 2;
    float* xres = (float*)p;

    convert_all<<<8448, 256, 0, stream>>>(X, Wq, Wk, Wv, Wo, Xb, Wqb, Wkb, Wvb, Wob);

    gemm_qkv<<<1152, 256, 0, stream>>>(Xb, Wqb, Wkb, Wvb, bq, bk, bv, Qh, Kh, Vtb);

    flash_attn_mfma<<<768, 256, 0, stream>>>(Qh, Kh, Vtb, mask, head_mask, ctx);

    gemm_out<<<768, 256, 0, stream>>>(ctx, Wob, bo, X, xres);

    ln_kernel<<<MROWS, 256, 0, stream>>>(xres, gamma, beta, out);
}